// Round 13
// baseline (1590.968 us; speedup 1.0000x reference)
//
#include <hip/hip_runtime.h>
#include <hip/hip_bf16.h>

#define NB 16
#define NC 64

typedef float f32x2 __attribute__((ext_vector_type(2)));
typedef float f32x4 __attribute__((ext_vector_type(4)));

static __device__ __forceinline__ f32x2 fma2(f32x2 a, f32x2 b, f32x2 c) {
    return __builtin_elementwise_fma(a, b, c);
}
static __device__ __forceinline__ float bfr2f(unsigned short h) {
    union { unsigned u; float f; } cv; cv.u = ((unsigned)h) << 16;
    return cv.f;
}
// 1-instruction packed fp32->bf16 (RNE) [gfx950 v_cvt_pk_bf16_f32]
static __device__ __forceinline__ unsigned cvt_pk_bf16(float lo, float hi) {
    unsigned r;
    asm("v_cvt_pk_bf16_f32 %0, %1, %2" : "=v"(r) : "v"(lo), "v"(hi));
    return r;
}

// ---------------------------------------------------------------------------
// Shift-addressed float4 staging of a 68-row x 72-col halo tile, stride 72.
// ---------------------------------------------------------------------------
template <int H>
static __device__ __forceinline__ void stage_tile(
    const float* __restrict__ src, size_t ibase, int sTop, int sLeft,
    float (*sIn)[72], int tid)
{
#pragma unroll
    for (int i = 0; i < 5; ++i) {
        int idx = i * 256 + tid;
        if (idx < 68 * 16) {
            int r = idx >> 4, c4 = (idx & 15) << 2;
            int gy = sTop + r, gx = sLeft + c4;
            float4 v = make_float4(0.f, 0.f, 0.f, 0.f);
            if ((unsigned)gy < (unsigned)H && (unsigned)gx < (unsigned)H)
                v = *(const float4*)(src + ibase + (size_t)gy * H + gx);
            *(float4*)(&sIn[r][c4]) = v;
        }
    }
    if (tid < 136) {
        int r = tid >> 1, c4 = 64 + ((tid & 1) << 2);
        int gy = sTop + r, gx = sLeft + c4;
        float4 v = make_float4(0.f, 0.f, 0.f, 0.f);
        if ((unsigned)gy < (unsigned)H && (unsigned)gx < (unsigned)H)
            v = *(const float4*)(src + ibase + (size_t)gy * H + gx);
        *(float4*)(&sIn[r][c4]) = v;
    }
}

// ---------------------------------------------------------------------------
// Shared compute: level DWT + 4 band convs (bands paired 01/23, weights
// PRE-SCALED) on a staged 68x72 tile. 2x2 outputs/thread.
// ---------------------------------------------------------------------------
static __device__ __forceinline__ void dwt_conv_compute(
    const float (*sIn)[72], const f32x2 w01[9], const f32x2 w23[9],
    f32x2 kk01[4], f32x2 kk23[4], float llc[4], int qi, int qj)
{
#pragma unroll
    for (int i = 0; i < 4; ++i) { kk01[i] = (f32x2)0.f; kk23[i] = (f32x2)0.f; }

    const int pr0 = 2 * qi, pc0 = 2 * qj + 2;
#pragma unroll
    for (int rp = 0; rp < 4; ++rp) {
        float xa[8], xb[8];
#pragma unroll
        for (int n = 0; n < 4; ++n) {
            float2 va = *(const float2*)&sIn[pr0 + 2 * rp][pc0 + 2 * n];
            float2 vb = *(const float2*)&sIn[pr0 + 2 * rp + 1][pc0 + 2 * n];
            xa[2 * n] = va.x; xa[2 * n + 1] = va.y;
            xb[2 * n] = vb.x; xb[2 * n + 1] = vb.y;
        }
        f32x2 D01[4], D23[4];
#pragma unroll
        for (int n = 0; n < 4; ++n) {
            float a = xa[2 * n], e = xa[2 * n + 1];
            float f = xb[2 * n], g = xb[2 * n + 1];
            float s0 = a + e, s1 = f + g, d0 = a - e, d1 = f - g;
            D01[n].x = s0 + s1; D01[n].y = s0 - s1;
            D23[n].x = d0 + d1; D23[n].y = d0 - d1;
        }
#pragma unroll
        for (int mi = 0; mi < 2; ++mi) {
            const int r = rp - mi;
            if (r >= 0 && r <= 2) {
#pragma unroll
                for (int mj = 0; mj < 2; ++mj) {
                    const int m = 2 * mi + mj;
#pragma unroll
                    for (int s = 0; s < 3; ++s) {
                        kk01[m] = fma2(w01[3 * r + s], D01[mj + s], kk01[m]);
                        kk23[m] = fma2(w23[3 * r + s], D23[mj + s], kk23[m]);
                    }
                }
                if (r == 1) {
                    llc[2 * mi + 0] = 0.5f * D01[1].x;
                    llc[2 * mi + 1] = 0.5f * D01[2].x;
                }
            }
        }
    }
}

// ---------------------------------------------------------------------------
// K2': level-1 DWT+conv with the LL halo computed DIRECTLY from x.
// Writes t1 (bf16 bands) + cur2 (fp32 LL2). Occupancy pinned to 8 blocks/CU.
// ---------------------------------------------------------------------------
__global__ __launch_bounds__(256, 8) void dwt_conv_from_x_kernel(
    const float* __restrict__ x, const float* __restrict__ ww,
    const float* __restrict__ wsc, unsigned short* __restrict__ t_out,
    float* __restrict__ curn)
{
    const int tile = blockIdx.x;            // 4 tiles (2x2) of 32x32 @64-res
    const int c = blockIdx.y, b = blockIdx.z;
    const int ty = tile >> 1, tx = tile & 1;
    const int oy0 = ty * 32, ox0 = tx * 32;
    const int tid = threadIdx.x;
    const int qi = 2 * (tid >> 4), qj = 2 * (tid & 15);

    __shared__ float sLL[68][72];

    const float s0f = 0.5f * wsc[c * 4 + 0], s1f = 0.5f * wsc[c * 4 + 1];
    const float s2f = 0.5f * wsc[c * 4 + 2], s3f = 0.5f * wsc[c * 4 + 3];
    f32x2 w01[9], w23[9];
#pragma unroll
    for (int i = 0; i < 9; ++i) {
        w01[i].x = ww[(c * 4 + 0) * 9 + i] * s0f;
        w01[i].y = ww[(c * 4 + 1) * 9 + i] * s1f;
        w23[i].x = ww[(c * 4 + 2) * 9 + i] * s2f;
        w23[i].y = ww[(c * 4 + 3) * 9 + i] * s3f;
    }

    const size_t xbase = (size_t)(b * NC + c) * 65536;
    const int gy0 = 4 * oy0 - 4;
    const int gx0 = 4 * ox0 - 8;
    // incremental (r, cp) walk: u += 256 == r += 7, cp += 4 (mod 36)
    {
        int r = tid / 36, cp = tid - (tid / 36) * 36;
#pragma unroll 1
        for (int u = tid; u < 68 * 36; u += 256) {
            int gy = gy0 + 2 * r, gx = gx0 + 4 * cp;
            float4 va = make_float4(0.f, 0.f, 0.f, 0.f);
            float4 vb = va;
            if ((unsigned)gy < 256u && (unsigned)gx < 256u) {
                va = *(const float4*)(x + xbase + (size_t)gy * 256 + gx);
                vb = *(const float4*)(x + xbase + (size_t)(gy + 1) * 256 + gx);
            }
            *(float2*)(&sLL[r][2 * cp]) =
                make_float2(0.5f * (va.x + va.y + vb.x + vb.y),
                            0.5f * (va.z + va.w + vb.z + vb.w));
            r += 7; cp += 4;
            if (cp >= 36) { cp -= 36; ++r; }
        }
    }
    __syncthreads();

    f32x2 kk01[4], kk23[4];
    float llc[4];
    dwt_conv_compute(sLL, w01, w23, kk01, kk23, llc, qi, qj);

    const size_t tbase = (size_t)(b * NC + c) * 4 * 4096;
    const size_t o00 = (size_t)(oy0 + qi) * 64 + (ox0 + qj);
#pragma unroll
    for (int mi = 0; mi < 2; ++mi) {
        *(unsigned*)(t_out + tbase +         o00 + (size_t)mi * 64) = cvt_pk_bf16(kk01[2*mi].x, kk01[2*mi+1].x);
        *(unsigned*)(t_out + tbase + 4096  + o00 + (size_t)mi * 64) = cvt_pk_bf16(kk01[2*mi].y, kk01[2*mi+1].y);
        *(unsigned*)(t_out + tbase + 8192  + o00 + (size_t)mi * 64) = cvt_pk_bf16(kk23[2*mi].x, kk23[2*mi+1].x);
        *(unsigned*)(t_out + tbase + 12288 + o00 + (size_t)mi * 64) = cvt_pk_bf16(kk23[2*mi].y, kk23[2*mi+1].y);
    }
    const size_t cbase = (size_t)(b * NC + c) * 4096 + o00;
    *(float2*)(curn + cbase)      = make_float2(llc[0], llc[1]);
    *(float2*)(curn + cbase + 64) = make_float2(llc[2], llc[3]);
}

// ---------------------------------------------------------------------------
// K3': level-2 DWT+conv (t2 in registers) fused with the 2-level IDWT recon.
// ---------------------------------------------------------------------------
__global__ __launch_bounds__(256) void level2_recon_kernel(
    const float* __restrict__ cur2, const float* __restrict__ ww,
    const float* __restrict__ wsc, const unsigned short* __restrict__ t1,
    unsigned short* __restrict__ nxt1)
{
    const int c = blockIdx.y, b = blockIdx.z;
    const int tid = threadIdx.x;
    const int qi = 2 * (tid >> 4), qj = 2 * (tid & 15);

    __shared__ float sIn[68][72];

    const float s0f = 0.5f * wsc[c * 4 + 0], s1f = 0.5f * wsc[c * 4 + 1];
    const float s2f = 0.5f * wsc[c * 4 + 2], s3f = 0.5f * wsc[c * 4 + 3];
    f32x2 w01[9], w23[9];
#pragma unroll
    for (int i = 0; i < 9; ++i) {
        w01[i].x = ww[(c * 4 + 0) * 9 + i] * s0f;
        w01[i].y = ww[(c * 4 + 1) * 9 + i] * s1f;
        w23[i].x = ww[(c * 4 + 2) * 9 + i] * s2f;
        w23[i].y = ww[(c * 4 + 3) * 9 + i] * s3f;
    }

    const size_t ibase = (size_t)(b * NC + c) * 4096;
    stage_tile<64>(cur2, ibase, -2, -4, sIn, tid);
    __syncthreads();

    f32x2 kk01[4], kk23[4];
    float llc[4];
    dwt_conv_compute(sIn, w01, w23, kk01, kk23, llc, qi, qj);

    const size_t img = (size_t)(b * NC + c);
    const unsigned short* t1p = t1 + img * 16384;
    unsigned short* n1p = nxt1 + img * 16384;
#pragma unroll
    for (int di = 0; di < 4; ++di) {
        const int i1 = 2 * qi + di;
        const int col = 2 * qj;               // qj even -> 8B aligned
        uint2 r0 = *(const uint2*)(t1p +         (size_t)i1 * 64 + col);
        uint2 r1 = *(const uint2*)(t1p + 4096 +  (size_t)i1 * 64 + col);
        uint2 r2 = *(const uint2*)(t1p + 8192 +  (size_t)i1 * 64 + col);
        uint2 r3 = *(const uint2*)(t1p + 12288 + (size_t)i1 * 64 + col);
        float v0[4] = { bfr2f((unsigned short)(r0.x & 0xffff)), bfr2f((unsigned short)(r0.x >> 16)),
                        bfr2f((unsigned short)(r0.y & 0xffff)), bfr2f((unsigned short)(r0.y >> 16)) };
        float v1[4] = { bfr2f((unsigned short)(r1.x & 0xffff)), bfr2f((unsigned short)(r1.x >> 16)),
                        bfr2f((unsigned short)(r1.y & 0xffff)), bfr2f((unsigned short)(r1.y >> 16)) };
        float v2[4] = { bfr2f((unsigned short)(r2.x & 0xffff)), bfr2f((unsigned short)(r2.x >> 16)),
                        bfr2f((unsigned short)(r2.y & 0xffff)), bfr2f((unsigned short)(r2.y >> 16)) };
        float v3[4] = { bfr2f((unsigned short)(r3.x & 0xffff)), bfr2f((unsigned short)(r3.x >> 16)),
                        bfr2f((unsigned short)(r3.y & 0xffff)), bfr2f((unsigned short)(r3.y >> 16)) };
        float top[8], bot[8];
#pragma unroll
        for (int dj = 0; dj < 4; ++dj) {
            const int m = 2 * (di >> 1) + (dj >> 1);
            float m0 = kk01[m].x, m1 = kk01[m].y, m2 = kk23[m].x, m3 = kk23[m].y;
            float s1v = (di & 1) ? -m1 : m1;
            float s2v = (dj & 1) ? -m2 : m2;
            float s3v = ((di ^ dj) & 1) ? -m3 : m3;
            float k0 = v0[dj] + 0.5f * (m0 + s1v + s2v + s3v);
            float k1 = v1[dj], k2 = v2[dj], k3 = v3[dj];
            top[2 * dj]     = 0.5f * (k0 + k1 + k2 + k3);
            top[2 * dj + 1] = 0.5f * (k0 + k1 - k2 - k3);
            bot[2 * dj]     = 0.5f * (k0 - k1 + k2 - k3);
            bot[2 * dj + 1] = 0.5f * (k0 - k1 - k2 + k3);
        }
        const size_t ob = (size_t)(4 * qi + 2 * di) * 128 + 4 * qj;  // 16B aligned
        uint4 tv, bv;
        tv.x = cvt_pk_bf16(top[0], top[1]); tv.y = cvt_pk_bf16(top[2], top[3]);
        tv.z = cvt_pk_bf16(top[4], top[5]); tv.w = cvt_pk_bf16(top[6], top[7]);
        bv.x = cvt_pk_bf16(bot[0], bot[1]); bv.y = cvt_pk_bf16(bot[2], bot[3]);
        bv.z = cvt_pk_bf16(bot[4], bot[5]); bv.w = cvt_pk_bf16(bot[6], bot[7]);
        *(uint4*)(n1p + ob) = tv;
        *(uint4*)(n1p + ob + 128) = bv;
    }
}

// ---------------------------------------------------------------------------
// K6: final fuse, quad-pair version. Occupancy pinned: 8 blocks/CU (VGPR<=64).
// ---------------------------------------------------------------------------
__global__ __launch_bounds__(256, 8) void final_fuse_kernel(
    const float* __restrict__ x, const unsigned short* __restrict__ nxt1,
    const float* __restrict__ bw, const float* __restrict__ bb,
    const float* __restrict__ bs, const float* __restrict__ ww0,
    const float* __restrict__ ws0,
    unsigned short* __restrict__ ybf, float2* __restrict__ partials)
{
    const int tile = blockIdx.x, c = blockIdx.y, b = blockIdx.z;
    const int ty = tile >> 2, tx = tile & 3;
    const int oy0 = ty * 64, ox0 = tx * 64;
    const int hy0 = ty * 32, hx0 = tx * 32;
    const int tid = threadIdx.x;
    const int qj = tid & 31;
    const int pr = tid >> 5;

    __shared__ float sIn[68][72];
    __shared__ float2 sW4[4];

    const float scale = bs[c];
    const float bsc = bb[c] * scale;
    const float s0f = 0.25f * ws0[c * 4 + 0], s1f = 0.25f * ws0[c * 4 + 1];
    const float s2f = 0.25f * ws0[c * 4 + 2], s3f = 0.25f * ws0[c * 4 + 3];
    f32x2 w01[9], w23[9];
    float wb[9];
#pragma unroll
    for (int i = 0; i < 9; ++i) {
        w01[i].x = ww0[(c * 4 + 0) * 9 + i] * s0f;
        w01[i].y = ww0[(c * 4 + 1) * 9 + i] * s1f;
        w23[i].x = ww0[(c * 4 + 2) * 9 + i] * s2f;
        w23[i].y = ww0[(c * 4 + 3) * 9 + i] * s3f;
        wb[i] = bw[c * 9 + i] * scale;     // scale folded
    }

    const size_t xb = (size_t)(b * NC + c) * 65536;
    stage_tile<256>(x, xb, oy0 - 2, ox0 - 4, sIn, tid);

    // prefetch nxt1 (issue-early: hides under LDS staging + barrier)
    const size_t n1b = (size_t)(b * NC + c) * 16384 + hx0 + qj;
    const float n1p0A = bfr2f(nxt1[n1b + (size_t)(hy0 + 2 * pr) * 128]);
    const float n1p0B = bfr2f(nxt1[n1b + (size_t)(hy0 + 2 * pr + 1) * 128]);
    const float n1p1A = bfr2f(nxt1[n1b + (size_t)(hy0 + 2 * pr + 16) * 128]);
    const float n1p1B = bfr2f(nxt1[n1b + (size_t)(hy0 + 2 * pr + 17) * 128]);

    __syncthreads();

    f32x2 lsum2 = (f32x2)0.f, lss2 = (f32x2)0.f;

#pragma unroll
    for (int pass = 0; pass < 2; ++pass) {
        const int pair = pr + 8 * pass;
        const int prow0 = 4 * pair;
        const int pc0 = 2 * qj + 2;

        f32x2 kkA01 = (f32x2)0.f, kkA23 = (f32x2)0.f;
        f32x2 kkB01 = (f32x2)0.f, kkB23 = (f32x2)0.f;
        float acc[4][2];
#pragma unroll
        for (int p = 0; p < 4; ++p) { acc[p][0] = 0.f; acc[p][1] = 0.f; }

#pragma unroll
        for (int rp = 0; rp < 4; ++rp) {
            float xa[6], xv[6];
#pragma unroll
            for (int n = 0; n < 3; ++n) {
                float2 va = *(const float2*)&sIn[prow0 + 2 * rp][pc0 + 2 * n];
                float2 vb = *(const float2*)&sIn[prow0 + 2 * rp + 1][pc0 + 2 * n];
                xa[2 * n] = va.x; xa[2 * n + 1] = va.y;
                xv[2 * n] = vb.x; xv[2 * n + 1] = vb.y;
            }
            f32x2 D01[3], D23[3];
#pragma unroll
            for (int n = 0; n < 3; ++n) {
                float a = xa[2 * n], e = xa[2 * n + 1];
                float f = xv[2 * n], g = xv[2 * n + 1];
                float s0 = a + e, s1 = f + g, d0 = a - e, d1 = f - g;
                D01[n].x = s0 + s1; D01[n].y = s0 - s1;
                D23[n].x = d0 + d1; D23[n].y = d0 - d1;
            }
            if (rp <= 2) {
#pragma unroll
                for (int s = 0; s < 3; ++s) {
                    kkA01 = fma2(w01[3 * rp + s], D01[s], kkA01);
                    kkA23 = fma2(w23[3 * rp + s], D23[s], kkA23);
                }
            }
            if (rp >= 1) {
                const int r = rp - 1;
#pragma unroll
                for (int s = 0; s < 3; ++s) {
                    kkB01 = fma2(w01[3 * r + s], D01[s], kkB01);
                    kkB23 = fma2(w23[3 * r + s], D23[s], kkB23);
                }
            }
#pragma unroll
            for (int py = 0; py < 4; ++py) {
                const int rra = 2 * rp - py - 1;
                if (rra >= 0 && rra <= 2) {
#pragma unroll
                    for (int u = 0; u < 2; ++u)
                        acc[py][u] = fmaf(xa[u + 1], wb[3 * rra],
                                     fmaf(xa[u + 2], wb[3 * rra + 1],
                                     fmaf(xa[u + 3], wb[3 * rra + 2], acc[py][u])));
                }
                const int rrb = 2 * rp - py;
                if (rrb >= 0 && rrb <= 2) {
#pragma unroll
                    for (int u = 0; u < 2; ++u)
                        acc[py][u] = fmaf(xv[u + 1], wb[3 * rrb],
                                     fmaf(xv[u + 2], wb[3 * rrb + 1],
                                     fmaf(xv[u + 3], wb[3 * rrb + 2], acc[py][u])));
                }
            }
        }

        const float n1A = pass ? n1p1A : n1p0A;
        const float n1B = pass ? n1p1B : n1p0B;
        const size_t ybase = xb + (size_t)(oy0 + 4 * pair) * 256 + (ox0 + 2 * qj);
#pragma unroll
        for (int quad = 0; quad < 2; ++quad) {
            const f32x2 k01 = quad ? kkB01 : kkA01;
            const f32x2 k23 = quad ? kkB23 : kkA23;
            float c0 = k01.x + 0.5f * (quad ? n1B : n1A);
            float c1 = k01.y, c2 = k23.x, c3 = k23.y;
            float p = c0 + c1, m = c0 - c1, q = c2 + c3, r = c2 - c3;
            f32x2 vT, vB;
            vT.x = (acc[2 * quad][0]     + bsc) + (p + q);
            vT.y = (acc[2 * quad][1]     + bsc) + (p - q);
            vB.x = (acc[2 * quad + 1][0] + bsc) + (m + r);
            vB.y = (acc[2 * quad + 1][1] + bsc) + (m - r);
            lsum2 = lsum2 + vT + vB;
            lss2 = fma2(vT, vT, lss2);
            lss2 = fma2(vB, vB, lss2);
            __builtin_nontemporal_store(cvt_pk_bf16(vT.x, vT.y),
                (unsigned*)(ybf + ybase + (size_t)(2 * quad) * 256));
            __builtin_nontemporal_store(cvt_pk_bf16(vB.x, vB.y),
                (unsigned*)(ybf + ybase + (size_t)(2 * quad + 1) * 256));
        }
    }

    float lsum = lsum2.x + lsum2.y;
    float lss = lss2.x + lss2.y;
#pragma unroll
    for (int off = 32; off > 0; off >>= 1) {
        lsum += __shfl_xor(lsum, off);
        lss  += __shfl_xor(lss, off);
    }
    if ((tid & 63) == 0) sW4[tid >> 6] = make_float2(lsum, lss);
    __syncthreads();
    if (tid == 0) {
        float s = sW4[0].x + sW4[1].x + sW4[2].x + sW4[3].x;
        float q = sW4[0].y + sW4[1].y + sW4[2].y + sW4[3].y;
        partials[c * 256 + b * 16 + tile] = make_float2(s, q);
    }
}

// ---------------------------------------------------------------------------
// K7: per-channel BN stats -> (a,b). 64 blocks x 256 threads.
// ---------------------------------------------------------------------------
__global__ __launch_bounds__(256) void stats_kernel(
    const float2* __restrict__ partials, const float* __restrict__ gamma,
    const float* __restrict__ beta, float2* __restrict__ ab)
{
    const int c = blockIdx.x;
    const int tid = threadIdx.x;
    __shared__ float s1[256], s2[256];
    float2 p = partials[c * 256 + tid];
    s1[tid] = p.x;
    s2[tid] = p.y;
    __syncthreads();
    for (int off = 128; off > 0; off >>= 1) {
        if (tid < off) { s1[tid] += s1[tid + off]; s2[tid] += s2[tid + off]; }
        __syncthreads();
    }
    if (tid == 0) {
        const float N = (float)NB * 65536.0f;
        float mean = s1[0] / N;
        float var = s2[0] / N - mean * mean;
        float inv = rsqrtf(var + 1e-5f);
        float a = gamma[c] * inv;
        ab[c] = make_float2(a, beta[c] - mean * a);
    }
}

// ---------------------------------------------------------------------------
// K8: normalize + ReLU: bf16 y-staging -> fp32 d_out (nontemporal stores).
// ---------------------------------------------------------------------------
__global__ __launch_bounds__(256) void norm_out_kernel(
    const unsigned short* __restrict__ ybf, const float2* __restrict__ ab,
    float* __restrict__ out)
{
    const long total8 = (long)NB * NC * 65536 / 8;
    const long stride = (long)gridDim.x * 256;
    for (long i = blockIdx.x * 256L + threadIdx.x; i < total8; i += stride) {
        long e = i * 8;
        int c = (int)((e >> 16) & (NC - 1));
        float2 s = ab[c];
        uint4 v = *(const uint4*)(ybf + e);
        f32x4 o0, o1;
        o0.x = fmaxf(fmaf(bfr2f((unsigned short)(v.x & 0xffff)), s.x, s.y), 0.f);
        o0.y = fmaxf(fmaf(bfr2f((unsigned short)(v.x >> 16)),    s.x, s.y), 0.f);
        o0.z = fmaxf(fmaf(bfr2f((unsigned short)(v.y & 0xffff)), s.x, s.y), 0.f);
        o0.w = fmaxf(fmaf(bfr2f((unsigned short)(v.y >> 16)),    s.x, s.y), 0.f);
        o1.x = fmaxf(fmaf(bfr2f((unsigned short)(v.z & 0xffff)), s.x, s.y), 0.f);
        o1.y = fmaxf(fmaf(bfr2f((unsigned short)(v.z >> 16)),    s.x, s.y), 0.f);
        o1.z = fmaxf(fmaf(bfr2f((unsigned short)(v.w & 0xffff)), s.x, s.y), 0.f);
        o1.w = fmaxf(fmaf(bfr2f((unsigned short)(v.w >> 16)),    s.x, s.y), 0.f);
        __builtin_nontemporal_store(o0, (f32x4*)(out + e));
        __builtin_nontemporal_store(o1, (f32x4*)(out + e + 4));
    }
}

extern "C" void kernel_launch(void* const* d_in, const int* in_sizes, int n_in,
                              void* d_out, int out_size, void* d_ws, size_t ws_size,
                              hipStream_t stream)
{
    const float* x    = (const float*)d_in[0];
    const float* bw   = (const float*)d_in[1];
    const float* bb   = (const float*)d_in[2];
    const float* bs   = (const float*)d_in[3];
    const float* ww0  = (const float*)d_in[4];
    const float* ww1  = (const float*)d_in[5];
    const float* ww2  = (const float*)d_in[6];
    const float* ws0  = (const float*)d_in[7];
    const float* ws1  = (const float*)d_in[8];
    const float* ws2  = (const float*)d_in[9];
    const float* gamma = (const float*)d_in[10];
    const float* beta  = (const float*)d_in[11];

    char* w = (char*)d_ws;
    unsigned short* ybf  = (unsigned short*)(w);                   // 134.2 MB (born K6)
    unsigned short* t1   = (unsigned short*)(w + 134217728);       // 33.6 MB bf16
    float*          cur2 = (float*)(w + 167772160);                // 16.8 MB fp32
    unsigned short* nxt1 = (unsigned short*)(w + 184549376);       // 33.6 MB bf16
    float2*         partials = (float2*)(w + 218103808);           // 128 KB
    float2*         ab       = (float2*)(w + 218234880);

    // K2': level 1 directly from x (LL computed in LDS)
    dwt_conv_from_x_kernel<<<dim3(4, NC, NB), 256, 0, stream>>>(x, ww1, ws1, t1, cur2);
    // K3': level 2 bands in registers + fused 2-level recon -> nxt1
    level2_recon_kernel<<<dim3(1, NC, NB), 256, 0, stream>>>(cur2, ww2, ws2, t1, nxt1);
    // K6: base conv + level-0 dwt/conv/idwt -> ybf (bf16) + partials
    final_fuse_kernel<<<dim3(16, NC, NB), 256, 0, stream>>>(x, nxt1, bw, bb, bs, ww0, ws0, ybf, partials);
    // K7: BN stats
    stats_kernel<<<dim3(64), 256, 0, stream>>>(partials, gamma, beta, ab);
    // K8: normalize + relu -> d_out (fp32)
    norm_out_kernel<<<dim3(2048), 256, 0, stream>>>(ybf, ab, (float*)d_out);
}

// Round 14
// 302.913 us; speedup vs baseline: 5.2522x; 5.2522x over previous
//
#include <hip/hip_runtime.h>
#include <hip/hip_bf16.h>

#define NB 16
#define NC 64

typedef float f32x2 __attribute__((ext_vector_type(2)));
typedef float f32x4 __attribute__((ext_vector_type(4)));

static __device__ __forceinline__ f32x2 fma2(f32x2 a, f32x2 b, f32x2 c) {
    return __builtin_elementwise_fma(a, b, c);
}
static __device__ __forceinline__ float bfr2f(unsigned short h) {
    union { unsigned u; float f; } cv; cv.u = ((unsigned)h) << 16;
    return cv.f;
}
// 1-instruction packed fp32->bf16 (RNE) [gfx950 v_cvt_pk_bf16_f32]
static __device__ __forceinline__ unsigned cvt_pk_bf16(float lo, float hi) {
    unsigned r;
    asm("v_cvt_pk_bf16_f32 %0, %1, %2" : "=v"(r) : "v"(lo), "v"(hi));
    return r;
}

// ---------------------------------------------------------------------------
// Shift-addressed float4 staging of a 68-row x 72-col halo tile, stride 72.
// ---------------------------------------------------------------------------
template <int H>
static __device__ __forceinline__ void stage_tile(
    const float* __restrict__ src, size_t ibase, int sTop, int sLeft,
    float (*sIn)[72], int tid)
{
#pragma unroll
    for (int i = 0; i < 5; ++i) {
        int idx = i * 256 + tid;
        if (idx < 68 * 16) {
            int r = idx >> 4, c4 = (idx & 15) << 2;
            int gy = sTop + r, gx = sLeft + c4;
            float4 v = make_float4(0.f, 0.f, 0.f, 0.f);
            if ((unsigned)gy < (unsigned)H && (unsigned)gx < (unsigned)H)
                v = *(const float4*)(src + ibase + (size_t)gy * H + gx);
            *(float4*)(&sIn[r][c4]) = v;
        }
    }
    if (tid < 136) {
        int r = tid >> 1, c4 = 64 + ((tid & 1) << 2);
        int gy = sTop + r, gx = sLeft + c4;
        float4 v = make_float4(0.f, 0.f, 0.f, 0.f);
        if ((unsigned)gy < (unsigned)H && (unsigned)gx < (unsigned)H)
            v = *(const float4*)(src + ibase + (size_t)gy * H + gx);
        *(float4*)(&sIn[r][c4]) = v;
    }
}

// ---------------------------------------------------------------------------
// Shared compute: level DWT + 4 band convs (bands paired 01/23, weights
// PRE-SCALED) on a staged 68x72 tile. 2x2 outputs/thread.
// ---------------------------------------------------------------------------
static __device__ __forceinline__ void dwt_conv_compute(
    const float (*sIn)[72], const f32x2 w01[9], const f32x2 w23[9],
    f32x2 kk01[4], f32x2 kk23[4], float llc[4], int qi, int qj)
{
#pragma unroll
    for (int i = 0; i < 4; ++i) { kk01[i] = (f32x2)0.f; kk23[i] = (f32x2)0.f; }

    const int pr0 = 2 * qi, pc0 = 2 * qj + 2;
#pragma unroll
    for (int rp = 0; rp < 4; ++rp) {
        float xa[8], xb[8];
#pragma unroll
        for (int n = 0; n < 4; ++n) {
            float2 va = *(const float2*)&sIn[pr0 + 2 * rp][pc0 + 2 * n];
            float2 vb = *(const float2*)&sIn[pr0 + 2 * rp + 1][pc0 + 2 * n];
            xa[2 * n] = va.x; xa[2 * n + 1] = va.y;
            xb[2 * n] = vb.x; xb[2 * n + 1] = vb.y;
        }
        f32x2 D01[4], D23[4];
#pragma unroll
        for (int n = 0; n < 4; ++n) {
            float a = xa[2 * n], e = xa[2 * n + 1];
            float f = xb[2 * n], g = xb[2 * n + 1];
            float s0 = a + e, s1 = f + g, d0 = a - e, d1 = f - g;
            D01[n].x = s0 + s1; D01[n].y = s0 - s1;
            D23[n].x = d0 + d1; D23[n].y = d0 - d1;
        }
#pragma unroll
        for (int mi = 0; mi < 2; ++mi) {
            const int r = rp - mi;
            if (r >= 0 && r <= 2) {
#pragma unroll
                for (int mj = 0; mj < 2; ++mj) {
                    const int m = 2 * mi + mj;
#pragma unroll
                    for (int s = 0; s < 3; ++s) {
                        kk01[m] = fma2(w01[3 * r + s], D01[mj + s], kk01[m]);
                        kk23[m] = fma2(w23[3 * r + s], D23[mj + s], kk23[m]);
                    }
                }
                if (r == 1) {
                    llc[2 * mi + 0] = 0.5f * D01[1].x;
                    llc[2 * mi + 1] = 0.5f * D01[2].x;
                }
            }
        }
    }
}

// ---------------------------------------------------------------------------
// K2': level-1 DWT+conv with the LL halo computed DIRECTLY from x.
// Writes t1 (bf16 bands) + cur2 (fp32 LL2).
// ---------------------------------------------------------------------------
__global__ __launch_bounds__(256) void dwt_conv_from_x_kernel(
    const float* __restrict__ x, const float* __restrict__ ww,
    const float* __restrict__ wsc, unsigned short* __restrict__ t_out,
    float* __restrict__ curn)
{
    const int tile = blockIdx.x;            // 4 tiles (2x2) of 32x32 @64-res
    const int c = blockIdx.y, b = blockIdx.z;
    const int ty = tile >> 1, tx = tile & 1;
    const int oy0 = ty * 32, ox0 = tx * 32;
    const int tid = threadIdx.x;
    const int qi = 2 * (tid >> 4), qj = 2 * (tid & 15);

    __shared__ float sLL[68][72];

    const float s0f = 0.5f * wsc[c * 4 + 0], s1f = 0.5f * wsc[c * 4 + 1];
    const float s2f = 0.5f * wsc[c * 4 + 2], s3f = 0.5f * wsc[c * 4 + 3];
    f32x2 w01[9], w23[9];
#pragma unroll
    for (int i = 0; i < 9; ++i) {
        w01[i].x = ww[(c * 4 + 0) * 9 + i] * s0f;
        w01[i].y = ww[(c * 4 + 1) * 9 + i] * s1f;
        w23[i].x = ww[(c * 4 + 2) * 9 + i] * s2f;
        w23[i].y = ww[(c * 4 + 3) * 9 + i] * s3f;
    }

    const size_t xbase = (size_t)(b * NC + c) * 65536;
    const int gy0 = 4 * oy0 - 4;
    const int gx0 = 4 * ox0 - 8;
    for (int u = tid; u < 68 * 36; u += 256) {
        int r = u / 36, cp = u - r * 36;
        int gy = gy0 + 2 * r, gx = gx0 + 4 * cp;
        float4 va = make_float4(0.f, 0.f, 0.f, 0.f);
        float4 vb = va;
        if ((unsigned)gy < 256u && (unsigned)gx < 256u) {
            va = *(const float4*)(x + xbase + (size_t)gy * 256 + gx);
            vb = *(const float4*)(x + xbase + (size_t)(gy + 1) * 256 + gx);
        }
        *(float2*)(&sLL[r][2 * cp]) =
            make_float2(0.5f * (va.x + va.y + vb.x + vb.y),
                        0.5f * (va.z + va.w + vb.z + vb.w));
    }
    __syncthreads();

    f32x2 kk01[4], kk23[4];
    float llc[4];
    dwt_conv_compute(sLL, w01, w23, kk01, kk23, llc, qi, qj);

    const size_t tbase = (size_t)(b * NC + c) * 4 * 4096;
    const size_t o00 = (size_t)(oy0 + qi) * 64 + (ox0 + qj);
#pragma unroll
    for (int mi = 0; mi < 2; ++mi) {
        *(unsigned*)(t_out + tbase +         o00 + (size_t)mi * 64) = cvt_pk_bf16(kk01[2*mi].x, kk01[2*mi+1].x);
        *(unsigned*)(t_out + tbase + 4096  + o00 + (size_t)mi * 64) = cvt_pk_bf16(kk01[2*mi].y, kk01[2*mi+1].y);
        *(unsigned*)(t_out + tbase + 8192  + o00 + (size_t)mi * 64) = cvt_pk_bf16(kk23[2*mi].x, kk23[2*mi+1].x);
        *(unsigned*)(t_out + tbase + 12288 + o00 + (size_t)mi * 64) = cvt_pk_bf16(kk23[2*mi].y, kk23[2*mi+1].y);
    }
    const size_t cbase = (size_t)(b * NC + c) * 4096 + o00;
    *(float2*)(curn + cbase)      = make_float2(llc[0], llc[1]);
    *(float2*)(curn + cbase + 64) = make_float2(llc[2], llc[3]);
}

// ---------------------------------------------------------------------------
// K3': level-2 DWT+conv (t2 in registers) fused with the 2-level IDWT recon.
// ---------------------------------------------------------------------------
__global__ __launch_bounds__(256) void level2_recon_kernel(
    const float* __restrict__ cur2, const float* __restrict__ ww,
    const float* __restrict__ wsc, const unsigned short* __restrict__ t1,
    unsigned short* __restrict__ nxt1)
{
    const int c = blockIdx.y, b = blockIdx.z;
    const int tid = threadIdx.x;
    const int qi = 2 * (tid >> 4), qj = 2 * (tid & 15);

    __shared__ float sIn[68][72];

    const float s0f = 0.5f * wsc[c * 4 + 0], s1f = 0.5f * wsc[c * 4 + 1];
    const float s2f = 0.5f * wsc[c * 4 + 2], s3f = 0.5f * wsc[c * 4 + 3];
    f32x2 w01[9], w23[9];
#pragma unroll
    for (int i = 0; i < 9; ++i) {
        w01[i].x = ww[(c * 4 + 0) * 9 + i] * s0f;
        w01[i].y = ww[(c * 4 + 1) * 9 + i] * s1f;
        w23[i].x = ww[(c * 4 + 2) * 9 + i] * s2f;
        w23[i].y = ww[(c * 4 + 3) * 9 + i] * s3f;
    }

    const size_t ibase = (size_t)(b * NC + c) * 4096;
    stage_tile<64>(cur2, ibase, -2, -4, sIn, tid);
    __syncthreads();

    f32x2 kk01[4], kk23[4];
    float llc[4];
    dwt_conv_compute(sIn, w01, w23, kk01, kk23, llc, qi, qj);

    const size_t img = (size_t)(b * NC + c);
    const unsigned short* t1p = t1 + img * 16384;
    unsigned short* n1p = nxt1 + img * 16384;
#pragma unroll
    for (int di = 0; di < 4; ++di) {
        const int i1 = 2 * qi + di;
        const int col = 2 * qj;               // qj even -> 8B aligned
        uint2 r0 = *(const uint2*)(t1p +         (size_t)i1 * 64 + col);
        uint2 r1 = *(const uint2*)(t1p + 4096 +  (size_t)i1 * 64 + col);
        uint2 r2 = *(const uint2*)(t1p + 8192 +  (size_t)i1 * 64 + col);
        uint2 r3 = *(const uint2*)(t1p + 12288 + (size_t)i1 * 64 + col);
        float v0[4] = { bfr2f((unsigned short)(r0.x & 0xffff)), bfr2f((unsigned short)(r0.x >> 16)),
                        bfr2f((unsigned short)(r0.y & 0xffff)), bfr2f((unsigned short)(r0.y >> 16)) };
        float v1[4] = { bfr2f((unsigned short)(r1.x & 0xffff)), bfr2f((unsigned short)(r1.x >> 16)),
                        bfr2f((unsigned short)(r1.y & 0xffff)), bfr2f((unsigned short)(r1.y >> 16)) };
        float v2[4] = { bfr2f((unsigned short)(r2.x & 0xffff)), bfr2f((unsigned short)(r2.x >> 16)),
                        bfr2f((unsigned short)(r2.y & 0xffff)), bfr2f((unsigned short)(r2.y >> 16)) };
        float v3[4] = { bfr2f((unsigned short)(r3.x & 0xffff)), bfr2f((unsigned short)(r3.x >> 16)),
                        bfr2f((unsigned short)(r3.y & 0xffff)), bfr2f((unsigned short)(r3.y >> 16)) };
        float top[8], bot[8];
#pragma unroll
        for (int dj = 0; dj < 4; ++dj) {
            const int m = 2 * (di >> 1) + (dj >> 1);
            float m0 = kk01[m].x, m1 = kk01[m].y, m2 = kk23[m].x, m3 = kk23[m].y;
            float s1v = (di & 1) ? -m1 : m1;
            float s2v = (dj & 1) ? -m2 : m2;
            float s3v = ((di ^ dj) & 1) ? -m3 : m3;
            float k0 = v0[dj] + 0.5f * (m0 + s1v + s2v + s3v);
            float k1 = v1[dj], k2 = v2[dj], k3 = v3[dj];
            top[2 * dj]     = 0.5f * (k0 + k1 + k2 + k3);
            top[2 * dj + 1] = 0.5f * (k0 + k1 - k2 - k3);
            bot[2 * dj]     = 0.5f * (k0 - k1 + k2 - k3);
            bot[2 * dj + 1] = 0.5f * (k0 - k1 - k2 + k3);
        }
        const size_t ob = (size_t)(4 * qi + 2 * di) * 128 + 4 * qj;  // 16B aligned
        uint4 tv, bv;
        tv.x = cvt_pk_bf16(top[0], top[1]); tv.y = cvt_pk_bf16(top[2], top[3]);
        tv.z = cvt_pk_bf16(top[4], top[5]); tv.w = cvt_pk_bf16(top[6], top[7]);
        bv.x = cvt_pk_bf16(bot[0], bot[1]); bv.y = cvt_pk_bf16(bot[2], bot[3]);
        bv.z = cvt_pk_bf16(bot[4], bot[5]); bv.w = cvt_pk_bf16(bot[6], bot[7]);
        *(uint4*)(n1p + ob) = tv;
        *(uint4*)(n1p + ob + 128) = bv;
    }
}

// ---------------------------------------------------------------------------
// K6: final fuse, quad-pair version with pk-paired band math, pre-scaled
// weights, nxt1 prefetch, and nontemporal ybf stores. NO VGPR cap (round-13
// lesson: capping below natural allocation spills to scratch, 5x regression).
// ---------------------------------------------------------------------------
__global__ __launch_bounds__(256) void final_fuse_kernel(
    const float* __restrict__ x, const unsigned short* __restrict__ nxt1,
    const float* __restrict__ bw, const float* __restrict__ bb,
    const float* __restrict__ bs, const float* __restrict__ ww0,
    const float* __restrict__ ws0,
    unsigned short* __restrict__ ybf, float2* __restrict__ partials)
{
    const int tile = blockIdx.x, c = blockIdx.y, b = blockIdx.z;
    const int ty = tile >> 2, tx = tile & 3;
    const int oy0 = ty * 64, ox0 = tx * 64;
    const int hy0 = ty * 32, hx0 = tx * 32;
    const int tid = threadIdx.x;
    const int qj = tid & 31;
    const int pr = tid >> 5;

    __shared__ float sIn[68][72];
    __shared__ float2 sW4[4];

    const float scale = bs[c];
    const float bsc = bb[c] * scale;
    const float s0f = 0.25f * ws0[c * 4 + 0], s1f = 0.25f * ws0[c * 4 + 1];
    const float s2f = 0.25f * ws0[c * 4 + 2], s3f = 0.25f * ws0[c * 4 + 3];
    f32x2 w01[9], w23[9];
    float wb[9];
#pragma unroll
    for (int i = 0; i < 9; ++i) {
        w01[i].x = ww0[(c * 4 + 0) * 9 + i] * s0f;
        w01[i].y = ww0[(c * 4 + 1) * 9 + i] * s1f;
        w23[i].x = ww0[(c * 4 + 2) * 9 + i] * s2f;
        w23[i].y = ww0[(c * 4 + 3) * 9 + i] * s3f;
        wb[i] = bw[c * 9 + i] * scale;     // scale folded
    }

    const size_t xb = (size_t)(b * NC + c) * 65536;
    stage_tile<256>(x, xb, oy0 - 2, ox0 - 4, sIn, tid);

    // prefetch nxt1 (issue-early: hides under LDS staging + barrier)
    const size_t n1b = (size_t)(b * NC + c) * 16384 + hx0 + qj;
    const float n1p0A = bfr2f(nxt1[n1b + (size_t)(hy0 + 2 * pr) * 128]);
    const float n1p0B = bfr2f(nxt1[n1b + (size_t)(hy0 + 2 * pr + 1) * 128]);
    const float n1p1A = bfr2f(nxt1[n1b + (size_t)(hy0 + 2 * pr + 16) * 128]);
    const float n1p1B = bfr2f(nxt1[n1b + (size_t)(hy0 + 2 * pr + 17) * 128]);

    __syncthreads();

    f32x2 lsum2 = (f32x2)0.f, lss2 = (f32x2)0.f;

#pragma unroll
    for (int pass = 0; pass < 2; ++pass) {
        const int pair = pr + 8 * pass;
        const int prow0 = 4 * pair;
        const int pc0 = 2 * qj + 2;

        f32x2 kkA01 = (f32x2)0.f, kkA23 = (f32x2)0.f;
        f32x2 kkB01 = (f32x2)0.f, kkB23 = (f32x2)0.f;
        float acc[4][2];
#pragma unroll
        for (int p = 0; p < 4; ++p) { acc[p][0] = 0.f; acc[p][1] = 0.f; }

#pragma unroll
        for (int rp = 0; rp < 4; ++rp) {
            float xa[6], xv[6];
#pragma unroll
            for (int n = 0; n < 3; ++n) {
                float2 va = *(const float2*)&sIn[prow0 + 2 * rp][pc0 + 2 * n];
                float2 vb = *(const float2*)&sIn[prow0 + 2 * rp + 1][pc0 + 2 * n];
                xa[2 * n] = va.x; xa[2 * n + 1] = va.y;
                xv[2 * n] = vb.x; xv[2 * n + 1] = vb.y;
            }
            f32x2 D01[3], D23[3];
#pragma unroll
            for (int n = 0; n < 3; ++n) {
                float a = xa[2 * n], e = xa[2 * n + 1];
                float f = xv[2 * n], g = xv[2 * n + 1];
                float s0 = a + e, s1 = f + g, d0 = a - e, d1 = f - g;
                D01[n].x = s0 + s1; D01[n].y = s0 - s1;
                D23[n].x = d0 + d1; D23[n].y = d0 - d1;
            }
            if (rp <= 2) {
#pragma unroll
                for (int s = 0; s < 3; ++s) {
                    kkA01 = fma2(w01[3 * rp + s], D01[s], kkA01);
                    kkA23 = fma2(w23[3 * rp + s], D23[s], kkA23);
                }
            }
            if (rp >= 1) {
                const int r = rp - 1;
#pragma unroll
                for (int s = 0; s < 3; ++s) {
                    kkB01 = fma2(w01[3 * r + s], D01[s], kkB01);
                    kkB23 = fma2(w23[3 * r + s], D23[s], kkB23);
                }
            }
#pragma unroll
            for (int py = 0; py < 4; ++py) {
                const int rra = 2 * rp - py - 1;
                if (rra >= 0 && rra <= 2) {
#pragma unroll
                    for (int u = 0; u < 2; ++u)
                        acc[py][u] = fmaf(xa[u + 1], wb[3 * rra],
                                     fmaf(xa[u + 2], wb[3 * rra + 1],
                                     fmaf(xa[u + 3], wb[3 * rra + 2], acc[py][u])));
                }
                const int rrb = 2 * rp - py;
                if (rrb >= 0 && rrb <= 2) {
#pragma unroll
                    for (int u = 0; u < 2; ++u)
                        acc[py][u] = fmaf(xv[u + 1], wb[3 * rrb],
                                     fmaf(xv[u + 2], wb[3 * rrb + 1],
                                     fmaf(xv[u + 3], wb[3 * rrb + 2], acc[py][u])));
                }
            }
        }

        const float n1A = pass ? n1p1A : n1p0A;
        const float n1B = pass ? n1p1B : n1p0B;
        const size_t ybase = xb + (size_t)(oy0 + 4 * pair) * 256 + (ox0 + 2 * qj);
#pragma unroll
        for (int quad = 0; quad < 2; ++quad) {
            const f32x2 k01 = quad ? kkB01 : kkA01;
            const f32x2 k23 = quad ? kkB23 : kkA23;
            float c0 = k01.x + 0.5f * (quad ? n1B : n1A);
            float c1 = k01.y, c2 = k23.x, c3 = k23.y;
            float p = c0 + c1, m = c0 - c1, q = c2 + c3, r = c2 - c3;
            f32x2 vT, vB;
            vT.x = (acc[2 * quad][0]     + bsc) + (p + q);
            vT.y = (acc[2 * quad][1]     + bsc) + (p - q);
            vB.x = (acc[2 * quad + 1][0] + bsc) + (m + r);
            vB.y = (acc[2 * quad + 1][1] + bsc) + (m - r);
            lsum2 = lsum2 + vT + vB;
            lss2 = fma2(vT, vT, lss2);
            lss2 = fma2(vB, vB, lss2);
            __builtin_nontemporal_store(cvt_pk_bf16(vT.x, vT.y),
                (unsigned*)(ybf + ybase + (size_t)(2 * quad) * 256));
            __builtin_nontemporal_store(cvt_pk_bf16(vB.x, vB.y),
                (unsigned*)(ybf + ybase + (size_t)(2 * quad + 1) * 256));
        }
    }

    float lsum = lsum2.x + lsum2.y;
    float lss = lss2.x + lss2.y;
#pragma unroll
    for (int off = 32; off > 0; off >>= 1) {
        lsum += __shfl_xor(lsum, off);
        lss  += __shfl_xor(lss, off);
    }
    if ((tid & 63) == 0) sW4[tid >> 6] = make_float2(lsum, lss);
    __syncthreads();
    if (tid == 0) {
        float s = sW4[0].x + sW4[1].x + sW4[2].x + sW4[3].x;
        float q = sW4[0].y + sW4[1].y + sW4[2].y + sW4[3].y;
        partials[c * 256 + b * 16 + tile] = make_float2(s, q);
    }
}

// ---------------------------------------------------------------------------
// K7: per-channel BN stats -> (a,b). 64 blocks x 256 threads.
// ---------------------------------------------------------------------------
__global__ __launch_bounds__(256) void stats_kernel(
    const float2* __restrict__ partials, const float* __restrict__ gamma,
    const float* __restrict__ beta, float2* __restrict__ ab)
{
    const int c = blockIdx.x;
    const int tid = threadIdx.x;
    __shared__ float s1[256], s2[256];
    float2 p = partials[c * 256 + tid];
    s1[tid] = p.x;
    s2[tid] = p.y;
    __syncthreads();
    for (int off = 128; off > 0; off >>= 1) {
        if (tid < off) { s1[tid] += s1[tid + off]; s2[tid] += s2[tid + off]; }
        __syncthreads();
    }
    if (tid == 0) {
        const float N = (float)NB * 65536.0f;
        float mean = s1[0] / N;
        float var = s2[0] / N - mean * mean;
        float inv = rsqrtf(var + 1e-5f);
        float a = gamma[c] * inv;
        ab[c] = make_float2(a, beta[c] - mean * a);
    }
}

// ---------------------------------------------------------------------------
// K8: normalize + ReLU: bf16 y-staging -> fp32 d_out (nontemporal stores).
// ---------------------------------------------------------------------------
__global__ __launch_bounds__(256) void norm_out_kernel(
    const unsigned short* __restrict__ ybf, const float2* __restrict__ ab,
    float* __restrict__ out)
{
    const long total8 = (long)NB * NC * 65536 / 8;
    const long stride = (long)gridDim.x * 256;
    for (long i = blockIdx.x * 256L + threadIdx.x; i < total8; i += stride) {
        long e = i * 8;
        int c = (int)((e >> 16) & (NC - 1));
        float2 s = ab[c];
        uint4 v = *(const uint4*)(ybf + e);
        f32x4 o0, o1;
        o0.x = fmaxf(fmaf(bfr2f((unsigned short)(v.x & 0xffff)), s.x, s.y), 0.f);
        o0.y = fmaxf(fmaf(bfr2f((unsigned short)(v.x >> 16)),    s.x, s.y), 0.f);
        o0.z = fmaxf(fmaf(bfr2f((unsigned short)(v.y & 0xffff)), s.x, s.y), 0.f);
        o0.w = fmaxf(fmaf(bfr2f((unsigned short)(v.y >> 16)),    s.x, s.y), 0.f);
        o1.x = fmaxf(fmaf(bfr2f((unsigned short)(v.z & 0xffff)), s.x, s.y), 0.f);
        o1.y = fmaxf(fmaf(bfr2f((unsigned short)(v.z >> 16)),    s.x, s.y), 0.f);
        o1.z = fmaxf(fmaf(bfr2f((unsigned short)(v.w & 0xffff)), s.x, s.y), 0.f);
        o1.w = fmaxf(fmaf(bfr2f((unsigned short)(v.w >> 16)),    s.x, s.y), 0.f);
        __builtin_nontemporal_store(o0, (f32x4*)(out + e));
        __builtin_nontemporal_store(o1, (f32x4*)(out + e + 4));
    }
}

extern "C" void kernel_launch(void* const* d_in, const int* in_sizes, int n_in,
                              void* d_out, int out_size, void* d_ws, size_t ws_size,
                              hipStream_t stream)
{
    const float* x    = (const float*)d_in[0];
    const float* bw   = (const float*)d_in[1];
    const float* bb   = (const float*)d_in[2];
    const float* bs   = (const float*)d_in[3];
    const float* ww0  = (const float*)d_in[4];
    const float* ww1  = (const float*)d_in[5];
    const float* ww2  = (const float*)d_in[6];
    const float* ws0  = (const float*)d_in[7];
    const float* ws1  = (const float*)d_in[8];
    const float* ws2  = (const float*)d_in[9];
    const float* gamma = (const float*)d_in[10];
    const float* beta  = (const float*)d_in[11];

    char* w = (char*)d_ws;
    unsigned short* ybf  = (unsigned short*)(w);                   // 134.2 MB (born K6)
    unsigned short* t1   = (unsigned short*)(w + 134217728);       // 33.6 MB bf16
    float*          cur2 = (float*)(w + 167772160);                // 16.8 MB fp32
    unsigned short* nxt1 = (unsigned short*)(w + 184549376);       // 33.6 MB bf16
    float2*         partials = (float2*)(w + 218103808);           // 128 KB
    float2*         ab       = (float2*)(w + 218234880);

    // K2': level 1 directly from x (LL computed in LDS)
    dwt_conv_from_x_kernel<<<dim3(4, NC, NB), 256, 0, stream>>>(x, ww1, ws1, t1, cur2);
    // K3': level 2 bands in registers + fused 2-level recon -> nxt1
    level2_recon_kernel<<<dim3(1, NC, NB), 256, 0, stream>>>(cur2, ww2, ws2, t1, nxt1);
    // K6: base conv + level-0 dwt/conv/idwt -> ybf (bf16) + partials
    final_fuse_kernel<<<dim3(16, NC, NB), 256, 0, stream>>>(x, nxt1, bw, bb, bs, ww0, ws0, ybf, partials);
    // K7: BN stats
    stats_kernel<<<dim3(64), 256, 0, stream>>>(partials, gamma, beta, ab);
    // K8: normalize + relu -> d_out (fp32)
    norm_out_kernel<<<dim3(2048), 256, 0, stream>>>(ybf, ab, (float*)d_out);
}